// Round 2
// baseline (366.241 us; speedup 1.0000x reference)
//
#include <hip/hip_runtime.h>

#define NBINS 10
#define NREP  8          // histogram replicas per block (lane & 7)
#define REPW  20         // words per replica: 10 x (prob f32, packed tp<<16|cnt u32)
                         // stride 20: replica base banks r*20%32 = {0,20,8,28,16,4,24,12} all distinct
#define PART_STRIDE 32   // per-block partial row stride (padded from 30)

// Round 5: fire-and-forget LDS atomics. Per element: ~18 VALU for the exact
// bin computation + 2 non-returning DS atomic adds (ds_add_f32 prob,
// ds_add_u32 packed tp/count). No read-back => no lgkmcnt dependency chain
// in the loop (the round-3 killer), and no 10-way unrolled select
// (the round-4 killer, ~50 VALU/elem). 8 replicas cut same-address
// serialization within a wave to ~1-2 lanes/address. LDS = 640 B,
// VGPR ~25 => full occupancy (8 blocks/CU, 32 waves/CU).
__global__ __launch_bounds__(256) void calib_hist(
    const float* __restrict__ outputs,
    const float* __restrict__ labels,
    float* __restrict__ partials,
    long n)
{
    __shared__ __align__(16) unsigned int s_hist[NREP * REPW];   // 640 B

    const int tid = threadIdx.x;
    for (int j = tid; j < NREP * REPW; j += 256) s_hist[j] = 0u;
    __syncthreads();

    const float low0 = -1e-6f;
    const float step = (1.0f - low0) / 10.0f;   // fp32 linspace delta (const-folded)

    unsigned int* __restrict__ rep  = &s_hist[(tid & (NREP - 1)) * REPW];
    float*        __restrict__ repf = (float*)rep;

    const long total4 = n >> 2;
    const float4* o4 = (const float4*)outputs;
    const float4* l4 = (const float4*)labels;
    const long gid = (long)blockIdx.x * blockDim.x + tid;
    const long gsz = (long)gridDim.x * blockDim.x;

    long i = gid;
    if (i < total4) {
        float4 o = o4[i];
        float4 l = l4[i];
        for (;;) {
            const long nexti = i + gsz;
            const bool have_next = (nexti < total4);
            float4 no, nl;
            if (have_next) { no = o4[nexti]; nl = l4[nexti]; }

            float xs[4] = {o.x, o.y, o.z, o.w};
            float ys[4] = {l.x, l.y, l.z, l.w};
#pragma unroll
            for (int k = 0; k < 4; ++k) {
                float x = xs[k];
                bool valid = (x > low0) & (x <= 1.0f);
                int e = (int)(x * 10.0f);
                e = e < 0 ? 0 : (e > 9 ? 9 : e);
                float fe  = (float)e;
                float hb0 = fmaf(fe,        step, low0);   // high[e-1]
                float hb1 = fmaf(fe + 1.0f, step, low0);   // high[e]
                int b = e + ((x > hb1) ? 1 : 0) - (((e > 0) & (x <= hb0)) ? 1 : 0);
                b = b < 0 ? 0 : (b > 9 ? 9 : b);
                float        px = valid ? x : 0.0f;
                unsigned int pc = valid ? ((ys[k] > 0.5f) ? 0x10001u : 1u) : 0u;
                // fire-and-forget: result discarded -> non-rtn ds_add, no chain
                __hip_atomic_fetch_add(&repf[2 * b], px,
                                       __ATOMIC_RELAXED, __HIP_MEMORY_SCOPE_WORKGROUP);
                __hip_atomic_fetch_add(&rep[2 * b + 1], pc,
                                       __ATOMIC_RELAXED, __HIP_MEMORY_SCOPE_WORKGROUP);
            }

            if (!have_next) break;
            o = no; l = nl; i = nexti;
        }
    }

    // scalar tail for n % 4 != 0 (not hit for this shape)
    const long tail0 = total4 << 2;
    for (long t = tail0 + gid; t < n; t += gsz) {
        float x = outputs[t];
        float y = labels [t];
        bool valid = (x > low0) & (x <= 1.0f);
        int e = (int)(x * 10.0f);
        e = e < 0 ? 0 : (e > 9 ? 9 : e);
        float fe  = (float)e;
        float hb0 = fmaf(fe,        step, low0);
        float hb1 = fmaf(fe + 1.0f, step, low0);
        int b = e + ((x > hb1) ? 1 : 0) - (((e > 0) & (x <= hb0)) ? 1 : 0);
        b = b < 0 ? 0 : (b > 9 ? 9 : b);
        float        px = valid ? x : 0.0f;
        unsigned int pc = valid ? ((y > 0.5f) ? 0x10001u : 1u) : 0u;
        __hip_atomic_fetch_add(&repf[2 * b], px,
                               __ATOMIC_RELAXED, __HIP_MEMORY_SCOPE_WORKGROUP);
        __hip_atomic_fetch_add(&rep[2 * b + 1], pc,
                               __ATOMIC_RELAXED, __HIP_MEMORY_SCOPE_WORKGROUP);
    }

    __syncthreads();   // drains lgkmcnt; all atomics visible

    // Reduce 8 replicas -> 30 partial slots. Packed u32 replica sums can be
    // added directly (cnt<=16384, tp<=16384 per block: no cross-field carry),
    // but summing per-field as float is just as cheap here.
    if (tid < 3 * NBINS) {
        const int b = tid % NBINS;
        float s = 0.0f;
#pragma unroll
        for (int r = 0; r < NREP; ++r) {
            if (tid < NBINS) {
                s += ((float*)s_hist)[r * REPW + 2 * b];
            } else {
                unsigned int c = s_hist[r * REPW + 2 * b + 1];
                s += (tid < 2 * NBINS) ? (float)(c >> 16) : (float)(c & 0xFFFFu);
            }
        }
        partials[(long)blockIdx.x * PART_STRIDE + tid] = s;
    }
}

// Kernel 2: one block per output slot; double-precision accumulate of partials.
__global__ __launch_bounds__(256) void calib_reduce(
    const float* __restrict__ partials, float* __restrict__ out, int nrows)
{
    const int s   = blockIdx.x;    // 0..29
    const int tid = threadIdx.x;
    double acc = 0.0;
    for (int r = tid; r < nrows; r += 256)
        acc += (double)partials[(long)r * PART_STRIDE + s];
#pragma unroll
    for (int off = 32; off > 0; off >>= 1)
        acc += __shfl_down(acc, off, 64);
    __shared__ double wsum[4];
    if ((tid & 63) == 0) wsum[tid >> 6] = acc;
    __syncthreads();
    if (tid == 0) out[s] = (float)(wsum[0] + wsum[1] + wsum[2] + wsum[3]);
}

extern "C" void kernel_launch(void* const* d_in, const int* in_sizes, int n_in,
                              void* d_out, int out_size, void* d_ws, size_t ws_size,
                              hipStream_t stream) {
    const float* outputs = (const float*)d_in[0];
    const float* labels  = (const float*)d_in[1];
    float* out = (float*)d_out;
    long n = (long)in_sizes[0];

    // grid = 2048 -> 8 blocks/CU, exactly 16 float4 per thread at this shape.
    // Per-block elems = 16384 < 65536 keeps the packed 16-bit fields exact
    // even in the degenerate all-one-bin case.
    int nblocks = 2048;
    size_t need = (size_t)nblocks * PART_STRIDE * sizeof(float);
    if (ws_size < need) {
        nblocks = (int)(ws_size / (PART_STRIDE * sizeof(float)));
        if (nblocks < 1) nblocks = 1;
    }
    float* partials = (float*)d_ws;

    calib_hist  <<<nblocks, 256, 0, stream>>>(outputs, labels, partials, n);
    calib_reduce<<<3 * NBINS, 256, 0, stream>>>(partials, out, nblocks);
}

// Round 3
// 288.457 us; speedup vs baseline: 1.2697x; 1.2697x over previous
//
#include <hip/hip_runtime.h>

#define NBINS 10
#define ROWW  20         // 10 x (prob f32, packed tp<<16|cnt u32) pairs, 8B-aligned
                         // 256*20*4 = 20480 B/block -> 8 blocks/CU by LDS
#define PART_STRIDE 32   // per-block partial row stride (padded from 30)
#define BATCH 4          // float4-quads per thread per iteration (16 elems)

// Round 6: round-3 accumulator (thread-private LDS row RMW: 1 ds_read_b64 +
// 1 ds_write_b64 per elem, no atomics, no 10-way select) + fixed memory
// pipeline: 8 dwordx4 loads issued per iteration (8 KB/wave in flight) and
// one batch of cross-iteration prefetch, so the wave always has loads
// outstanding. Rounds 3-5 were all stuck at 1.4-2.6 TB/s effective read BW
// with only 512 B/wave in flight; VALU (~20us) and LDS (~14-22us) budgets
// are both under the 43us HBM floor, so this should land memory-bound.
__device__ __forceinline__ void process4(const float4& o, const float4& l,
                                         unsigned int* __restrict__ row)
{
    const float low0 = -1e-6f;
    const float step = (1.0f - low0) / 10.0f;   // fp32 linspace delta (const-folded)
    float xs[4] = {o.x, o.y, o.z, o.w};
    float ys[4] = {l.x, l.y, l.z, l.w};
#pragma unroll
    for (int k = 0; k < 4; ++k) {
        float x = xs[k];
        bool valid = (x > low0) & (x <= 1.0f);
        int e = (int)(x * 10.0f);
        e = e < 0 ? 0 : (e > 9 ? 9 : e);
        float fe  = (float)e;
        float hb0 = fmaf(fe,        step, low0);   // high[e-1]
        float hb1 = fmaf(fe + 1.0f, step, low0);   // high[e]
        int b = e + ((x > hb1) ? 1 : 0) - (((e > 0) & (x <= hb0)) ? 1 : 0);
        b = b < 0 ? 0 : (b > 9 ? 9 : b);
        float        px = valid ? x : 0.0f;
        unsigned int pc = valid ? ((ys[k] > 0.5f) ? 0x10001u : 1u) : 0u;
        unsigned long long* p = (unsigned long long*)&row[2 * b];
        unsigned long long v = *p;                 // ds_read_b64
        float        pr = __uint_as_float((unsigned int)v) + px;
        unsigned int ct = (unsigned int)(v >> 32) + pc;
        *p = ((unsigned long long)ct << 32) | (unsigned long long)__float_as_uint(pr);
    }
}

__global__ __launch_bounds__(256) void calib_hist(
    const float* __restrict__ outputs,
    const float* __restrict__ labels,
    float* __restrict__ partials,
    long n)
{
    __shared__ __align__(16) unsigned int s_hist[256 * ROWW];   // 20480 B

    const int tid = threadIdx.x;
    for (int j = tid; j < 256 * ROWW; j += 256) s_hist[j] = 0u;
    __syncthreads();

    unsigned int* __restrict__ row = &s_hist[tid * ROWW];

    const long total4 = n >> 2;
    const float4* o4 = (const float4*)outputs;
    const float4* l4 = (const float4*)labels;
    const long gid = (long)blockIdx.x * blockDim.x + tid;
    const long gsz = (long)gridDim.x * blockDim.x;
    const long bstep = (long)BATCH * gsz;

    long i = gid;
    if (i + (BATCH - 1) * gsz < total4) {
        float4 co[BATCH], cl[BATCH];
#pragma unroll
        for (int q = 0; q < BATCH; ++q) {          // 8 loads in flight
            co[q] = o4[i + q * gsz];
            cl[q] = l4[i + q * gsz];
        }
        for (;;) {
            const long ni = i + bstep;
            const bool hn = (ni + (BATCH - 1) * gsz < total4);
            float4 no_[BATCH], nl_[BATCH];
            if (hn) {                               // prefetch next batch:
#pragma unroll
                for (int q = 0; q < BATCH; ++q) {   // 8 more loads in flight
                    no_[q] = o4[ni + q * gsz];
                    nl_[q] = l4[ni + q * gsz];
                }
            }
#pragma unroll
            for (int q = 0; q < BATCH; ++q)
                process4(co[q], cl[q], row);
            if (!hn) break;
#pragma unroll
            for (int q = 0; q < BATCH; ++q) { co[q] = no_[q]; cl[q] = nl_[q]; }
            i = ni;
        }
        i += bstep;                                 // first unprocessed quad
    }
    for (; i < total4; i += gsz) {                  // remainder quads (none at 2048 blocks)
        float4 o = o4[i];
        float4 l = l4[i];
        process4(o, l, row);
    }

    // scalar tail for n % 4 != 0 (not hit for this shape)
    const float low0 = -1e-6f;
    const float step = (1.0f - low0) / 10.0f;
    const long tail0 = total4 << 2;
    for (long t = tail0 + gid; t < n; t += gsz) {
        float x = outputs[t];
        float y = labels [t];
        bool valid = (x > low0) & (x <= 1.0f);
        int e = (int)(x * 10.0f);
        e = e < 0 ? 0 : (e > 9 ? 9 : e);
        float fe  = (float)e;
        float hb0 = fmaf(fe,        step, low0);
        float hb1 = fmaf(fe + 1.0f, step, low0);
        int b = e + ((x > hb1) ? 1 : 0) - (((e > 0) & (x <= hb0)) ? 1 : 0);
        b = b < 0 ? 0 : (b > 9 ? 9 : b);
        float        px = valid ? x : 0.0f;
        unsigned int pc = valid ? ((y > 0.5f) ? 0x10001u : 1u) : 0u;
        unsigned long long* p = (unsigned long long*)&row[2 * b];
        unsigned long long v = *p;
        float        pr = __uint_as_float((unsigned int)v) + px;
        unsigned int ct = (unsigned int)(v >> 32) + pc;
        *p = ((unsigned long long)ct << 32) | (unsigned long long)__float_as_uint(pr);
    }

    __syncthreads();

    // Block reduce without pad words (ROWW=20 has none):
    // stage 1: slot = tid&31 (0-9 prob, 10-19 tp, 20-29 cnt), group = tid>>5;
    //          each group sums 32 rows for its slot.
    const int slot  = tid & 31;
    const int group = tid >> 5;
    float acc = 0.0f;
    if (slot < 3 * NBINS) {
        const int b  = slot % NBINS;
        const int r0 = group * 32;
        for (int r = r0; r < r0 + 32; ++r) {
            unsigned int base = (unsigned int)r * ROWW + 2 * b;
            if (slot < NBINS) {
                acc += __uint_as_float(s_hist[base]);
            } else {
                unsigned int c = s_hist[base + 1];
                acc += (slot < 2 * NBINS) ? (float)(c >> 16) : (float)(c & 0xFFFFu);
            }
        }
    }
    // combine the two groups living in each wave (lane ^ 32)
    acc += __shfl_xor(acc, 32, 64);
    __syncthreads();                    // all rows read; s_hist reusable
    if ((tid & 63) < 32 && slot < 3 * NBINS)
        ((float*)s_hist)[(tid >> 6) * 32 + slot] = acc;   // 4 wave-partials/slot
    __syncthreads();
    if (tid < 3 * NBINS) {
        float* sh = (float*)s_hist;
        float s = sh[tid] + sh[32 + tid] + sh[64 + tid] + sh[96 + tid];
        partials[(long)blockIdx.x * PART_STRIDE + tid] = s;
    }
}

// Kernel 2: one block per output slot; double-precision accumulate of partials.
__global__ __launch_bounds__(256) void calib_reduce(
    const float* __restrict__ partials, float* __restrict__ out, int nrows)
{
    const int s   = blockIdx.x;    // 0..29
    const int tid = threadIdx.x;
    double acc = 0.0;
    for (int r = tid; r < nrows; r += 256)
        acc += (double)partials[(long)r * PART_STRIDE + s];
#pragma unroll
    for (int off = 32; off > 0; off >>= 1)
        acc += __shfl_down(acc, off, 64);
    __shared__ double wsum[4];
    if ((tid & 63) == 0) wsum[tid >> 6] = acc;
    __syncthreads();
    if (tid == 0) out[s] = (float)(wsum[0] + wsum[1] + wsum[2] + wsum[3]);
}

extern "C" void kernel_launch(void* const* d_in, const int* in_sizes, int n_in,
                              void* d_out, int out_size, void* d_ws, size_t ws_size,
                              hipStream_t stream) {
    const float* outputs = (const float*)d_in[0];
    const float* labels  = (const float*)d_in[1];
    float* out = (float*)d_out;
    long n = (long)in_sizes[0];

    // grid = 2048: exactly 16 quads/thread = 4 full batches, no remainder.
    // Per-thread elems = 64 << 65536 keeps the packed 16-bit counts exact.
    // (ws requirement 256 KB was already satisfied in prior rounds.)
    int nblocks = 2048;
    size_t need = (size_t)nblocks * PART_STRIDE * sizeof(float);
    if (ws_size < need) {
        nblocks = (int)(ws_size / (PART_STRIDE * sizeof(float)));
        if (nblocks < 1) nblocks = 1;
    }
    float* partials = (float*)d_ws;

    calib_hist  <<<nblocks, 256, 0, stream>>>(outputs, labels, partials, n);
    calib_reduce<<<3 * NBINS, 256, 0, stream>>>(partials, out, nblocks);
}

// Round 4
// 281.077 us; speedup vs baseline: 1.3030x; 1.0263x over previous
//
#include <hip/hip_runtime.h>

#define NBINS 10
#define ROWW  22         // dwords per thread-private LDS row: 10 x (u64 pair) + 2 pad
                         // odd*11 stride: bank-pair = (11*lane + b) % 16 bijective per
                         // 16 lanes => conflict-free b64 (the r0 103us layout)
#define PART_STRIDE 32   // per-block partial row stride (padded from 30)

// Round 7: r0 structure (103us) + single-u64-add RMW.
// Per-bin u64 = [cnt:16 | tp:16 | prob_fixed20:32]. The increment
// (hi = valid?(0x10000|ygt):0, lo = cvt(fma(px,2^20,0.5))) is computed
// BEFORE the ds_read lands, so the serial chain is just
// ds_read_b64 -> add64 (2 VALU) -> ds_write_b64 (was: +unpack/repack ~6 VALU).
// No field can carry: <=76 elems/thread (grid 1792) => cnt,tp<=76, prob<2^27.
// Plus 1-deep rotating prefetch (no 4-deep batch, no ROWW change).
__device__ __forceinline__ void process4(const float4& o, const float4& l,
                                         unsigned int* __restrict__ row)
{
    const float low0 = -1e-6f;
    const float step = (1.0f - low0) / 10.0f;   // fp32 linspace delta (const-folded)
    float xs[4] = {o.x, o.y, o.z, o.w};
    float ys[4] = {l.x, l.y, l.z, l.w};
#pragma unroll
    for (int k = 0; k < 4; ++k) {
        float x = xs[k];
        bool valid = (x > low0) & (x <= 1.0f);
        int e = (int)(x * 10.0f);
        e = e < 0 ? 0 : (e > 9 ? 9 : e);
        float fe  = (float)e;
        float hb0 = fmaf(fe,        step, low0);   // high[e-1]
        float hb1 = fmaf(fe + 1.0f, step, low0);   // high[e]
        int b = e + ((x > hb1) ? 1 : 0) - (((e > 0) & (x <= hb0)) ? 1 : 0);
        b = b < 0 ? 0 : (b > 9 ? 9 : b);
        float px = valid ? x : 0.0f;
        unsigned int lo = (unsigned int)fmaf(px, 1048576.0f, 0.5f); // fixed20, rn
        unsigned int hi = valid ? ((ys[k] > 0.5f) ? 0x10001u : 0x10000u) : 0u;
        unsigned long long inc = ((unsigned long long)hi << 32) | (unsigned long long)lo;
        unsigned long long* p = (unsigned long long*)&row[2 * b];
        *p += inc;          // ds_read_b64 + v_add_co/addc + ds_write_b64
    }
}

__global__ __launch_bounds__(256) void calib_hist(
    const float* __restrict__ outputs,
    const float* __restrict__ labels,
    float* __restrict__ partials,
    long n)
{
    __shared__ __align__(16) unsigned int s_hist[256 * ROWW];   // 22528 B -> 7 blocks/CU

    const int tid = threadIdx.x;
    for (int j = tid; j < 256 * ROWW; j += 256) s_hist[j] = 0u;
    __syncthreads();

    unsigned int* __restrict__ row = &s_hist[tid * ROWW];

    const long total4 = n >> 2;
    const float4* o4 = (const float4*)outputs;
    const float4* l4 = (const float4*)labels;
    const long gid = (long)blockIdx.x * blockDim.x + tid;
    const long gsz = (long)gridDim.x * blockDim.x;

    long i = gid;
    if (i < total4) {
        float4 o = o4[i];
        float4 l = l4[i];
        for (;;) {
            const long ni = i + gsz;
            const bool hn = (ni < total4);
            float4 no, nl;
            if (hn) { no = o4[ni]; nl = l4[ni]; }   // 2 loads in flight over process4
            process4(o, l, row);
            if (!hn) break;
            o = no; l = nl; i = ni;
        }
    }

    // scalar tail for n % 4 != 0 (not hit for this shape)
    const float low0 = -1e-6f;
    const float step = (1.0f - low0) / 10.0f;
    const long tail0 = total4 << 2;
    for (long t = tail0 + gid; t < n; t += gsz) {
        float x = outputs[t];
        float y = labels [t];
        bool valid = (x > low0) & (x <= 1.0f);
        int e = (int)(x * 10.0f);
        e = e < 0 ? 0 : (e > 9 ? 9 : e);
        float fe  = (float)e;
        float hb0 = fmaf(fe,        step, low0);
        float hb1 = fmaf(fe + 1.0f, step, low0);
        int b = e + ((x > hb1) ? 1 : 0) - (((e > 0) & (x <= hb0)) ? 1 : 0);
        b = b < 0 ? 0 : (b > 9 ? 9 : b);
        float px = valid ? x : 0.0f;
        unsigned int lo = (unsigned int)fmaf(px, 1048576.0f, 0.5f);
        unsigned int hi = valid ? ((y > 0.5f) ? 0x10001u : 0x10000u) : 0u;
        unsigned long long inc = ((unsigned long long)hi << 32) | (unsigned long long)lo;
        unsigned long long* p = (unsigned long long*)&row[2 * b];
        *p += inc;
    }

    __syncthreads();

    // Block reduce (r0 structure): 240 threads, slot = tid%30
    // (0-9 prob, 10-19 tp, 20-29 count), chunk = tid/30 sums 32 rows;
    // partial stashed in the row pad word (offset 20) of row (chunk*30+slot).
    if (tid < 240) {
        int slot  = tid % 30;
        int chunk = tid / 30;
        int b = slot % NBINS;
        float acc = 0.0f;
        int r0 = chunk * 32;
        for (int r = r0; r < r0 + 32; ++r) {
            unsigned int base = (unsigned int)r * ROWW + 2 * b;
            if (slot < NBINS) {
                acc += (float)s_hist[base];                    // prob fixed20 (lo32)
            } else {
                unsigned int c = s_hist[base + 1];             // [cnt:16|tp:16]
                acc += (slot < 2 * NBINS) ? (float)(c & 0xFFFFu)  // tp
                                          : (float)(c >> 16);     // count
            }
        }
        if (slot < NBINS) acc *= (1.0f / 1048576.0f);          // back to prob units
        ((float*)s_hist)[(unsigned int)(chunk * 30 + slot) * ROWW + 20] = acc;
    }
    __syncthreads();
    if (tid < 3 * NBINS) {
        float s = 0.0f;
#pragma unroll
        for (int c = 0; c < 8; ++c)
            s += ((float*)s_hist)[(unsigned int)(c * 30 + tid) * ROWW + 20];
        partials[(long)blockIdx.x * PART_STRIDE + tid] = s;
    }
}

// Kernel 2: one block per output slot; double-precision accumulate of partials.
__global__ __launch_bounds__(256) void calib_reduce(
    const float* __restrict__ partials, float* __restrict__ out, int nrows)
{
    const int s   = blockIdx.x;    // 0..29
    const int tid = threadIdx.x;
    double acc = 0.0;
    for (int r = tid; r < nrows; r += 256)
        acc += (double)partials[(long)r * PART_STRIDE + s];
#pragma unroll
    for (int off = 32; off > 0; off >>= 1)
        acc += __shfl_down(acc, off, 64);
    __shared__ double wsum[4];
    if ((tid & 63) == 0) wsum[tid >> 6] = acc;
    __syncthreads();
    if (tid == 0) out[s] = (float)(wsum[0] + wsum[1] + wsum[2] + wsum[3]);
}

extern "C" void kernel_launch(void* const* d_in, const int* in_sizes, int n_in,
                              void* d_out, int out_size, void* d_ws, size_t ws_size,
                              hipStream_t stream) {
    const float* outputs = (const float*)d_in[0];
    const float* labels  = (const float*)d_in[1];
    float* out = (float*)d_out;
    long n = (long)in_sizes[0];

    // 22528 B LDS/block -> 7 blocks/CU; grid = 7*256 so all blocks co-resident;
    // <=76 elems/thread keeps all packed fields exact.
    int nblocks = 1792;
    size_t need = (size_t)nblocks * PART_STRIDE * sizeof(float);
    if (ws_size < need) {
        nblocks = (int)(ws_size / (PART_STRIDE * sizeof(float)));
        if (nblocks < 1) nblocks = 1;
    }
    float* partials = (float*)d_ws;

    calib_hist  <<<nblocks, 256, 0, stream>>>(outputs, labels, partials, n);
    calib_reduce<<<3 * NBINS, 256, 0, stream>>>(partials, out, nblocks);
}

// Round 5
// 280.319 us; speedup vs baseline: 1.3065x; 1.0027x over previous
//
#include <hip/hip_runtime.h>

#define NBINS 10
#define ROWW  22         // dwords per thread-private LDS row: 10 x (u64 bin) + 2 pad
                         // odd*11 stride: bank-pair = (11*lane + b) % 16 bijective per
                         // 16 lanes => conflict-free b64 (the r0/r7 layout)
#define PART_STRIDE 32   // per-block partial row stride (padded from 30)

// Round 8: r7 base + ONE change: the per-element LDS update is now a
// NON-RETURNING ds_add_u64 atomic to the thread's PRIVATE row.
//   r7:  ds_read_b64 -> s_waitcnt lgkmcnt(0) -> add64 -> ds_write_b64
//        (every element stalls the wave on the LDS read round trip;
//         three structures all pinned at ~102us on this latency)
//   r8:  v_add-free fire-and-forget ds_add_u64, no lgkmcnt in the loop.
// Private rows => zero same-address collisions (round 2's atomic disaster
// was 32 lanes sharing a replica). One DS op per element instead of two.
// Per-bin u64 = [cnt:16 | tp:16 | prob_fixed20:32]; <=76 elems/thread
// (grid 1792) => cnt,tp <= 76, prob < 2^27: no field carry, exact.
__device__ __forceinline__ void process4(const float4& o, const float4& l,
                                         unsigned int* __restrict__ row)
{
    const float low0 = -1e-6f;
    const float step = (1.0f - low0) / 10.0f;   // fp32 linspace delta (const-folded)
    float xs[4] = {o.x, o.y, o.z, o.w};
    float ys[4] = {l.x, l.y, l.z, l.w};
#pragma unroll
    for (int k = 0; k < 4; ++k) {
        float x = xs[k];
        bool valid = (x > low0) & (x <= 1.0f);
        int e = (int)(x * 10.0f);
        e = e < 0 ? 0 : (e > 9 ? 9 : e);
        float fe  = (float)e;
        float hb0 = fmaf(fe,        step, low0);   // high[e-1]
        float hb1 = fmaf(fe + 1.0f, step, low0);   // high[e]
        int b = e + ((x > hb1) ? 1 : 0) - (((e > 0) & (x <= hb0)) ? 1 : 0);
        b = b < 0 ? 0 : (b > 9 ? 9 : b);
        float px = valid ? x : 0.0f;
        unsigned int lo = (unsigned int)fmaf(px, 1048576.0f, 0.5f); // fixed20, rn
        unsigned int hi = valid ? ((ys[k] > 0.5f) ? 0x10001u : 0x10000u) : 0u;
        unsigned long long inc = ((unsigned long long)hi << 32) | (unsigned long long)lo;
        // fire-and-forget: result unused -> ds_add_u64 (no rtn), no wait
        __hip_atomic_fetch_add((unsigned long long*)&row[2 * b], inc,
                               __ATOMIC_RELAXED, __HIP_MEMORY_SCOPE_WORKGROUP);
    }
}

__global__ __launch_bounds__(256) void calib_hist(
    const float* __restrict__ outputs,
    const float* __restrict__ labels,
    float* __restrict__ partials,
    long n)
{
    __shared__ __align__(16) unsigned int s_hist[256 * ROWW];   // 22528 B -> 7 blocks/CU

    const int tid = threadIdx.x;
    for (int j = tid; j < 256 * ROWW; j += 256) s_hist[j] = 0u;
    __syncthreads();

    unsigned int* __restrict__ row = &s_hist[tid * ROWW];

    const long total4 = n >> 2;
    const float4* o4 = (const float4*)outputs;
    const float4* l4 = (const float4*)labels;
    const long gid = (long)blockIdx.x * blockDim.x + tid;
    const long gsz = (long)gridDim.x * blockDim.x;

    long i = gid;
    if (i < total4) {
        float4 o = o4[i];
        float4 l = l4[i];
        for (;;) {
            const long ni = i + gsz;
            const bool hn = (ni < total4);
            float4 no, nl;
            if (hn) { no = o4[ni]; nl = l4[ni]; }   // loads in flight over process4
            process4(o, l, row);
            if (!hn) break;
            o = no; l = nl; i = ni;
        }
    }

    // scalar tail for n % 4 != 0 (not hit for this shape)
    const float low0 = -1e-6f;
    const float step = (1.0f - low0) / 10.0f;
    const long tail0 = total4 << 2;
    for (long t = tail0 + gid; t < n; t += gsz) {
        float x = outputs[t];
        float y = labels [t];
        bool valid = (x > low0) & (x <= 1.0f);
        int e = (int)(x * 10.0f);
        e = e < 0 ? 0 : (e > 9 ? 9 : e);
        float fe  = (float)e;
        float hb0 = fmaf(fe,        step, low0);
        float hb1 = fmaf(fe + 1.0f, step, low0);
        int b = e + ((x > hb1) ? 1 : 0) - (((e > 0) & (x <= hb0)) ? 1 : 0);
        b = b < 0 ? 0 : (b > 9 ? 9 : b);
        float px = valid ? x : 0.0f;
        unsigned int lo = (unsigned int)fmaf(px, 1048576.0f, 0.5f);
        unsigned int hi = valid ? ((y > 0.5f) ? 0x10001u : 0x10000u) : 0u;
        unsigned long long inc = ((unsigned long long)hi << 32) | (unsigned long long)lo;
        __hip_atomic_fetch_add((unsigned long long*)&row[2 * b], inc,
                               __ATOMIC_RELAXED, __HIP_MEMORY_SCOPE_WORKGROUP);
    }

    __syncthreads();   // drains lgkmcnt: all atomics complete & visible

    // Block reduce (r7 structure): 240 threads, slot = tid%30
    // (0-9 prob, 10-19 tp, 20-29 count), chunk = tid/30 sums 32 rows;
    // partial stashed in the row pad word (offset 20) of row (chunk*30+slot).
    if (tid < 240) {
        int slot  = tid % 30;
        int chunk = tid / 30;
        int b = slot % NBINS;
        float acc = 0.0f;
        int r0 = chunk * 32;
        for (int r = r0; r < r0 + 32; ++r) {
            unsigned int base = (unsigned int)r * ROWW + 2 * b;
            if (slot < NBINS) {
                acc += (float)s_hist[base];                    // prob fixed20 (lo32)
            } else {
                unsigned int c = s_hist[base + 1];             // [cnt:16|tp:16]
                acc += (slot < 2 * NBINS) ? (float)(c & 0xFFFFu)  // tp
                                          : (float)(c >> 16);     // count
            }
        }
        if (slot < NBINS) acc *= (1.0f / 1048576.0f);          // back to prob units
        ((float*)s_hist)[(unsigned int)(chunk * 30 + slot) * ROWW + 20] = acc;
    }
    __syncthreads();
    if (tid < 3 * NBINS) {
        float s = 0.0f;
#pragma unroll
        for (int c = 0; c < 8; ++c)
            s += ((float*)s_hist)[(unsigned int)(c * 30 + tid) * ROWW + 20];
        partials[(long)blockIdx.x * PART_STRIDE + tid] = s;
    }
}

// Kernel 2: one block per output slot; double-precision accumulate of partials.
__global__ __launch_bounds__(256) void calib_reduce(
    const float* __restrict__ partials, float* __restrict__ out, int nrows)
{
    const int s   = blockIdx.x;    // 0..29
    const int tid = threadIdx.x;
    double acc = 0.0;
    for (int r = tid; r < nrows; r += 256)
        acc += (double)partials[(long)r * PART_STRIDE + s];
#pragma unroll
    for (int off = 32; off > 0; off >>= 1)
        acc += __shfl_down(acc, off, 64);
    __shared__ double wsum[4];
    if ((tid & 63) == 0) wsum[tid >> 6] = acc;
    __syncthreads();
    if (tid == 0) out[s] = (float)(wsum[0] + wsum[1] + wsum[2] + wsum[3]);
}

extern "C" void kernel_launch(void* const* d_in, const int* in_sizes, int n_in,
                              void* d_out, int out_size, void* d_ws, size_t ws_size,
                              hipStream_t stream) {
    const float* outputs = (const float*)d_in[0];
    const float* labels  = (const float*)d_in[1];
    float* out = (float*)d_out;
    long n = (long)in_sizes[0];

    // 22528 B LDS/block -> 7 blocks/CU; grid = 7*256 so all blocks co-resident;
    // <=76 elems/thread keeps all packed fields exact.
    int nblocks = 1792;
    size_t need = (size_t)nblocks * PART_STRIDE * sizeof(float);
    if (ws_size < need) {
        nblocks = (int)(ws_size / (PART_STRIDE * sizeof(float)));
        if (nblocks < 1) nblocks = 1;
    }
    float* partials = (float*)d_ws;

    calib_hist  <<<nblocks, 256, 0, stream>>>(outputs, labels, partials, n);
    calib_reduce<<<3 * NBINS, 256, 0, stream>>>(partials, out, nblocks);
}